// Round 1
// baseline (391.640 us; speedup 1.0000x reference)
//
#include <hip/hip_runtime.h>
#include <hip/hip_bf16.h>

// SupPixPool: out[b,c,k] = max over pixels p with spx[b,p]==k of img[b,c,p].
// B=4, C=64, H=W=512, K=1024 segments.
//
// Two-phase: (1) per-block privatized LDS max-tables (order-encoded uint so
// unsigned atomicMax == float max incl. negatives), dumped to ws; (2) fold
// chunk partials + decode. Fallback: global atomicMax into d_out if ws small.

constexpr int Kseg = 1024;
constexpr int Bn   = 4;
constexpr int Cn   = 64;
constexpr int HWn  = 512 * 512;

constexpr int CH   = 8;            // channels per block
constexpr int TPB  = 512;          // threads per block
constexpr int PIX  = 16384;        // pixels per block chunk
constexpr int NCHUNK = HWn / PIX;  // 16
constexpr int NCG    = Cn / CH;    // 8
constexpr int NBLK   = Bn * NCG * NCHUNK; // 512

// enc(-inf) = ~0xFF800000 = 0x007FFFFF; monotonic: enc(a)<enc(b) <=> a<b.
constexpr unsigned ENEG = 0x007FFFFFu;

__device__ __forceinline__ unsigned enc(float f) {
    unsigned u = __float_as_uint(f);
    return u ^ ((unsigned)((int)u >> 31) | 0x80000000u);
}
__device__ __forceinline__ float dec(unsigned e) {
    unsigned u = (e & 0x80000000u) ? (e ^ 0x80000000u) : ~e;
    return __uint_as_float(u);
}

__global__ __launch_bounds__(TPB) void pool_partial(
    const float* __restrict__ img, const int* __restrict__ spx,
    unsigned* __restrict__ part) {
    __shared__ unsigned tbl[CH * Kseg];  // 32 KB
    const int bx    = blockIdx.x;
    const int chunk = bx % NCHUNK;
    const int cg    = (bx / NCHUNK) % NCG;
    const int b     = bx / (NCHUNK * NCG);

    for (int i = threadIdx.x; i < CH * Kseg; i += TPB) tbl[i] = ENEG;
    __syncthreads();

    const int pixbase = chunk * PIX;
    const int*   spx_b = spx + (size_t)b * HWn;
    const float* img_b = img + (size_t)(b * Cn + cg * CH) * HWn;

    constexpr int ITERS = PIX / (TPB * 4);  // 8
    for (int it = 0; it < ITERS; ++it) {
        const int p4 = pixbase + (it * TPB + threadIdx.x) * 4;
        int4 s = *(const int4*)(spx_b + p4);
        s.x &= (Kseg - 1); s.y &= (Kseg - 1);
        s.z &= (Kseg - 1); s.w &= (Kseg - 1);
#pragma unroll
        for (int j = 0; j < CH; ++j) {
            const float4 v = *(const float4*)(img_b + (size_t)j * HWn + p4);
            unsigned* t = tbl + j * Kseg;
            atomicMax(t + s.x, enc(v.x));
            atomicMax(t + s.y, enc(v.y));
            atomicMax(t + s.z, enc(v.z));
            atomicMax(t + s.w, enc(v.w));
        }
    }
    __syncthreads();

    unsigned* dst = part + (size_t)bx * (CH * Kseg);
    for (int i = threadIdx.x; i < CH * Kseg; i += TPB) dst[i] = tbl[i];
}

__global__ __launch_bounds__(256) void pool_reduce(
    const unsigned* __restrict__ part, float* __restrict__ out) {
    const int gid = blockIdx.x * 256 + threadIdx.x;  // [0, B*C*K)
    const int k = gid & (Kseg - 1);
    const int c = (gid >> 10) & (Cn - 1);
    const int b = gid >> 16;
    const int cg = c / CH, j = c % CH;

    unsigned acc = ENEG;
    const unsigned* p = part + ((size_t)(b * NCG + cg) * NCHUNK) * (CH * Kseg)
                      + j * Kseg + k;
    for (int ch = 0; ch < NCHUNK; ++ch)
        acc = max(acc, p[(size_t)ch * (CH * Kseg)]);
    out[gid] = dec(acc);
}

// -------- fallback path (ws too small): global atomic merge into d_out -----
__global__ __launch_bounds__(256) void init_enc_k(unsigned* __restrict__ o) {
    o[blockIdx.x * 256 + threadIdx.x] = ENEG;
}

__global__ __launch_bounds__(TPB) void pool_atomic(
    const float* __restrict__ img, const int* __restrict__ spx,
    unsigned* __restrict__ gtab) {
    __shared__ unsigned tbl[CH * Kseg];
    const int bx    = blockIdx.x;
    const int chunk = bx % NCHUNK;
    const int cg    = (bx / NCHUNK) % NCG;
    const int b     = bx / (NCHUNK * NCG);

    for (int i = threadIdx.x; i < CH * Kseg; i += TPB) tbl[i] = ENEG;
    __syncthreads();

    const int pixbase = chunk * PIX;
    const int*   spx_b = spx + (size_t)b * HWn;
    const float* img_b = img + (size_t)(b * Cn + cg * CH) * HWn;

    constexpr int ITERS = PIX / (TPB * 4);
    for (int it = 0; it < ITERS; ++it) {
        const int p4 = pixbase + (it * TPB + threadIdx.x) * 4;
        int4 s = *(const int4*)(spx_b + p4);
        s.x &= (Kseg - 1); s.y &= (Kseg - 1);
        s.z &= (Kseg - 1); s.w &= (Kseg - 1);
#pragma unroll
        for (int j = 0; j < CH; ++j) {
            const float4 v = *(const float4*)(img_b + (size_t)j * HWn + p4);
            unsigned* t = tbl + j * Kseg;
            atomicMax(t + s.x, enc(v.x));
            atomicMax(t + s.y, enc(v.y));
            atomicMax(t + s.z, enc(v.z));
            atomicMax(t + s.w, enc(v.w));
        }
    }
    __syncthreads();

    // tbl index i = j*K + k maps to out index (b*Cn + cg*CH)*K + i
    unsigned* dst = gtab + (size_t)(b * Cn + cg * CH) * Kseg;
    for (int i = threadIdx.x; i < CH * Kseg; i += TPB)
        atomicMax(dst + i, tbl[i]);
}

__global__ __launch_bounds__(256) void decode_inplace(unsigned* __restrict__ o) {
    const int i = blockIdx.x * 256 + threadIdx.x;
    const unsigned e = o[i];
    ((float*)o)[i] = dec(e);
}

extern "C" void kernel_launch(void* const* d_in, const int* in_sizes, int n_in,
                              void* d_out, int out_size, void* d_ws, size_t ws_size,
                              hipStream_t stream) {
    const float* img = (const float*)d_in[0];
    const int*   spx = (const int*)d_in[1];
    float*       out = (float*)d_out;

    const size_t need = (size_t)NBLK * CH * Kseg * sizeof(unsigned);  // ~16.8 MB
    const int nOut256 = (Bn * Cn * Kseg) / 256;                       // 1024

    if (ws_size >= need) {
        unsigned* part = (unsigned*)d_ws;
        pool_partial<<<NBLK, TPB, 0, stream>>>(img, spx, part);
        pool_reduce<<<nOut256, 256, 0, stream>>>(part, out);
    } else {
        unsigned* gt = (unsigned*)d_out;
        init_enc_k<<<nOut256, 256, 0, stream>>>(gt);
        pool_atomic<<<NBLK, TPB, 0, stream>>>(img, spx, gt);
        decode_inplace<<<nOut256, 256, 0, stream>>>(gt);
    }
}

// Round 2
// 375.059 us; speedup vs baseline: 1.0442x; 1.0442x over previous
//
#include <hip/hip_runtime.h>
#include <hip/hip_bf16.h>

// SupPixPool: out[b,c,k] = max over pixels p with spx[b,p]==k of img[b,c,p].
// B=4, C=64, H=W=512, K=1024.
//
// Round-2 structure: channels-across-lanes (c = tid&7) with an interleaved
// LDS table tbl[k][8], so each ds_max instruction scatters to ~distinct banks
// (8-lane groups each cover 8 banks) instead of random per-lane serialization.
// img loads remain perfectly coalesced (8 ch x 32 consecutive pixels / wave).

constexpr int Kseg = 1024;
constexpr int Bn   = 4;
constexpr int Cn   = 64;
constexpr int HWn  = 512 * 512;

constexpr int CH     = 8;             // channels per block
constexpr int NCG    = Cn / CH;       // 8
constexpr int TPB    = 1024;
constexpr int NCHUNK = 16;            // pixel chunks per (b, cg)
constexpr int PIX    = HWn / NCHUNK;  // 16384 pixels per block
constexpr int SP     = 4096;          // spx staging sub-chunk (16 KB)
constexpr int NSUB   = PIX / SP;      // 4
constexpr int NBLK   = Bn * NCG * NCHUNK;  // 512
constexpr int QPT    = TPB / CH;      // 128 pixel-quad lanes per channel
constexpr int ITERS  = SP / (QPT * 4);     // 8

// order-preserving float->uint encoding: enc monotonic, unsigned max == fmax
constexpr unsigned ENEG = 0x007FFFFFu;  // enc(-inf)

__device__ __forceinline__ unsigned enc(float f) {
    unsigned u = __float_as_uint(f);
    return u ^ ((unsigned)((int)u >> 31) | 0x80000000u);
}
__device__ __forceinline__ float dec(unsigned e) {
    unsigned u = (e & 0x80000000u) ? (e ^ 0x80000000u) : ~e;
    return __uint_as_float(u);
}

__global__ __launch_bounds__(TPB, 8) void pool_partial(
    const float* __restrict__ img, const int* __restrict__ spx,
    unsigned* __restrict__ part) {
    __shared__ unsigned tbl[Kseg * CH];  // 32 KB, interleaved [k][8]
    __shared__ int sspx[SP];             // 16 KB

    const int bx    = blockIdx.x;
    const int chunk = bx % NCHUNK;
    const int cg    = (bx / NCHUNK) % NCG;
    const int b     = bx / (NCHUNK * NCG);

    for (int i = threadIdx.x; i < Kseg * CH; i += TPB) tbl[i] = ENEG;

    const int c  = threadIdx.x & (CH - 1);   // channel lane 0..7
    const int pq = threadIdx.x >> 3;         // pixel-quad lane 0..127

    const float* imgc = img + ((size_t)(b * Cn + cg * CH + c)) * HWn
                            + (size_t)chunk * PIX;
    const int*   spxb = spx + (size_t)b * HWn + (size_t)chunk * PIX;

    for (int sub = 0; sub < NSUB; ++sub) {
        __syncthreads();  // tbl init done / previous sub-chunk consumed
        ((int4*)sspx)[threadIdx.x] =
            ((const int4*)(spxb + sub * SP))[threadIdx.x];
        __syncthreads();

        const float* imgs = imgc + sub * SP;
#pragma unroll
        for (int it = 0; it < ITERS; ++it) {
            const int q = pq + it * QPT;               // quad in sub-chunk
            const float4 v = *(const float4*)(imgs + 4 * q);
            int4 k = *(const int4*)(sspx + 4 * q);     // ds_read_b128, bcast
            k.x &= (Kseg - 1); k.y &= (Kseg - 1);
            k.z &= (Kseg - 1); k.w &= (Kseg - 1);
            atomicMax(tbl + (k.x * CH + c), enc(v.x));
            atomicMax(tbl + (k.y * CH + c), enc(v.y));
            atomicMax(tbl + (k.z * CH + c), enc(v.z));
            atomicMax(tbl + (k.w * CH + c), enc(v.w));
        }
    }
    __syncthreads();

    unsigned* dst = part + (size_t)bx * (Kseg * CH);
    for (int i = threadIdx.x; i < Kseg * CH; i += TPB) dst[i] = tbl[i];
}

__global__ __launch_bounds__(256) void pool_reduce(
    const unsigned* __restrict__ part, float* __restrict__ out) {
    const int gid = blockIdx.x * 256 + threadIdx.x;  // [0, B*C*K)
    const int k = gid & (Kseg - 1);
    const int cc = (gid >> 10) & (Cn - 1);
    const int b = gid >> 16;
    const int cg = cc >> 3, j = cc & (CH - 1);

    unsigned acc = ENEG;
    const unsigned* p = part
        + ((size_t)(b * NCG + cg) * NCHUNK) * (Kseg * CH) + k * CH + j;
    for (int ch = 0; ch < NCHUNK; ++ch)
        acc = max(acc, p[(size_t)ch * (Kseg * CH)]);
    out[gid] = dec(acc);
}

// -------- fallback path (ws too small): global atomic merge into d_out -----
__global__ __launch_bounds__(256) void init_enc_k(unsigned* __restrict__ o) {
    o[blockIdx.x * 256 + threadIdx.x] = ENEG;
}

__global__ __launch_bounds__(TPB, 8) void pool_atomic(
    const float* __restrict__ img, const int* __restrict__ spx,
    unsigned* __restrict__ gtab) {
    __shared__ unsigned tbl[Kseg * CH];
    __shared__ int sspx[SP];

    const int bx    = blockIdx.x;
    const int chunk = bx % NCHUNK;
    const int cg    = (bx / NCHUNK) % NCG;
    const int b     = bx / (NCHUNK * NCG);

    for (int i = threadIdx.x; i < Kseg * CH; i += TPB) tbl[i] = ENEG;

    const int c  = threadIdx.x & (CH - 1);
    const int pq = threadIdx.x >> 3;

    const float* imgc = img + ((size_t)(b * Cn + cg * CH + c)) * HWn
                            + (size_t)chunk * PIX;
    const int*   spxb = spx + (size_t)b * HWn + (size_t)chunk * PIX;

    for (int sub = 0; sub < NSUB; ++sub) {
        __syncthreads();
        ((int4*)sspx)[threadIdx.x] =
            ((const int4*)(spxb + sub * SP))[threadIdx.x];
        __syncthreads();

        const float* imgs = imgc + sub * SP;
#pragma unroll
        for (int it = 0; it < ITERS; ++it) {
            const int q = pq + it * QPT;
            const float4 v = *(const float4*)(imgs + 4 * q);
            int4 k = *(const int4*)(sspx + 4 * q);
            k.x &= (Kseg - 1); k.y &= (Kseg - 1);
            k.z &= (Kseg - 1); k.w &= (Kseg - 1);
            atomicMax(tbl + (k.x * CH + c), enc(v.x));
            atomicMax(tbl + (k.y * CH + c), enc(v.y));
            atomicMax(tbl + (k.z * CH + c), enc(v.z));
            atomicMax(tbl + (k.w * CH + c), enc(v.w));
        }
    }
    __syncthreads();

    // tbl[k*CH + j] -> out index (b*Cn + cg*CH + j)*K + k
    unsigned* base = gtab + (size_t)(b * Cn + cg * CH) * Kseg;
    for (int i = threadIdx.x; i < Kseg * CH; i += TPB) {
        const int k = i >> 3, j = i & (CH - 1);
        atomicMax(base + (size_t)j * Kseg + k, tbl[i]);
    }
}

__global__ __launch_bounds__(256) void decode_inplace(unsigned* __restrict__ o) {
    const int i = blockIdx.x * 256 + threadIdx.x;
    const unsigned e = o[i];
    ((float*)o)[i] = dec(e);
}

extern "C" void kernel_launch(void* const* d_in, const int* in_sizes, int n_in,
                              void* d_out, int out_size, void* d_ws, size_t ws_size,
                              hipStream_t stream) {
    const float* img = (const float*)d_in[0];
    const int*   spx = (const int*)d_in[1];
    float*       out = (float*)d_out;

    const size_t need = (size_t)NBLK * Kseg * CH * sizeof(unsigned);  // ~16.8 MB
    const int nOut256 = (Bn * Cn * Kseg) / 256;                       // 1024

    if (ws_size >= need) {
        unsigned* part = (unsigned*)d_ws;
        pool_partial<<<NBLK, TPB, 0, stream>>>(img, spx, part);
        pool_reduce<<<nOut256, 256, 0, stream>>>(part, out);
    } else {
        unsigned* gt = (unsigned*)d_out;
        init_enc_k<<<nOut256, 256, 0, stream>>>(gt);
        pool_atomic<<<NBLK, TPB, 0, stream>>>(img, spx, gt);
        decode_inplace<<<nOut256, 256, 0, stream>>>(gt);
    }
}

// Round 3
// 372.792 us; speedup vs baseline: 1.0506x; 1.0061x over previous
//
#include <hip/hip_runtime.h>
#include <hip/hip_bf16.h>

// SupPixPool: out[b,c,k] = max over pixels p with spx[b,p]==k of img[b,c,p].
// B=4, C=64, H=W=512, K=1024.
//
// Round-3: (a) LDS table stride padded 8->9 so each ds_max wave-op's 8
// quad-group windows start at 9k mod 32 (collision only if k===k' mod 32,
// ~1.1-way, vs 4 bank-classes / ~3.5-way before). (b) spx read directly from
// global (8 same-address lanes coalesce to one 16B request; spx is
// LLC-resident) -- removes LDS staging, per-iter ds_read, and all inner
// barriers; waves run free between init and dump.

constexpr int Kseg = 1024;
constexpr int Bn   = 4;
constexpr int Cn   = 64;
constexpr int HWn  = 512 * 512;

constexpr int CH     = 8;             // channels per block
constexpr int NCG    = Cn / CH;       // 8
constexpr int TPB    = 1024;
constexpr int NCHUNK = 16;            // pixel chunks per (b, cg)
constexpr int PIX    = HWn / NCHUNK;  // 16384 pixels per block
constexpr int STR    = 9;             // padded table stride (36 KB)
constexpr int TBLW   = Kseg * STR;    // 9216 words
constexpr int NBLK   = Bn * NCG * NCHUNK;  // 512
constexpr int QPT    = TPB / CH;      // 128 pixel-quads in flight
constexpr int ITERS  = PIX / (QPT * 4);    // 32

// order-preserving float->uint encoding: enc monotonic, unsigned max == fmax
constexpr unsigned ENEG = 0x007FFFFFu;  // enc(-inf)

__device__ __forceinline__ unsigned enc(float f) {
    unsigned u = __float_as_uint(f);
    return u ^ ((unsigned)((int)u >> 31) | 0x80000000u);
}
__device__ __forceinline__ float dec(unsigned e) {
    unsigned u = (e & 0x80000000u) ? (e ^ 0x80000000u) : ~e;
    return __uint_as_float(u);
}

__global__ __launch_bounds__(TPB, 8) void pool_partial(
    const float* __restrict__ img, const int* __restrict__ spx,
    unsigned* __restrict__ part) {
    __shared__ unsigned tbl[TBLW];  // 36 KB, [k][9] padded

    const int bx    = blockIdx.x;
    const int chunk = bx % NCHUNK;
    const int cg    = (bx / NCHUNK) % NCG;
    const int b     = bx / (NCHUNK * NCG);

    for (int i = threadIdx.x; i < TBLW; i += TPB) tbl[i] = ENEG;
    __syncthreads();

    const int c  = threadIdx.x & (CH - 1);   // channel lane 0..7
    const int pq = threadIdx.x >> 3;         // pixel-quad lane 0..127

    const float* imgc = img + ((size_t)(b * Cn + cg * CH + c)) * HWn
                            + (size_t)chunk * PIX;
    const int*   spxb = spx + (size_t)b * HWn + (size_t)chunk * PIX;

#pragma unroll 4
    for (int it = 0; it < ITERS; ++it) {
        const int q = pq + it * QPT;                 // quad index in chunk
        const float4 v = *(const float4*)(imgc + 4 * q);
        int4 k = *(const int4*)(spxb + 4 * q);       // 8 lanes same addr
        k.x &= (Kseg - 1); k.y &= (Kseg - 1);
        k.z &= (Kseg - 1); k.w &= (Kseg - 1);
        atomicMax(tbl + (k.x * STR + c), enc(v.x));
        atomicMax(tbl + (k.y * STR + c), enc(v.y));
        atomicMax(tbl + (k.z * STR + c), enc(v.z));
        atomicMax(tbl + (k.w * STR + c), enc(v.w));
    }
    __syncthreads();

    unsigned* dst = part + (size_t)bx * TBLW;
    for (int i = threadIdx.x; i < TBLW; i += TPB) dst[i] = tbl[i];
}

__global__ __launch_bounds__(256) void pool_reduce(
    const unsigned* __restrict__ part, float* __restrict__ out) {
    const int gid = blockIdx.x * 256 + threadIdx.x;  // [0, B*C*K)
    const int k  = gid & (Kseg - 1);
    const int cc = (gid >> 10) & (Cn - 1);
    const int b  = gid >> 16;
    const int cg = cc >> 3, j = cc & (CH - 1);

    unsigned acc = ENEG;
    const unsigned* p = part
        + ((size_t)(b * NCG + cg) * NCHUNK) * TBLW + k * STR + j;
    for (int ch = 0; ch < NCHUNK; ++ch)
        acc = max(acc, p[(size_t)ch * TBLW]);
    out[gid] = dec(acc);
}

// -------- fallback path (ws too small): global atomic merge into d_out -----
__global__ __launch_bounds__(256) void init_enc_k(unsigned* __restrict__ o) {
    o[blockIdx.x * 256 + threadIdx.x] = ENEG;
}

__global__ __launch_bounds__(TPB, 8) void pool_atomic(
    const float* __restrict__ img, const int* __restrict__ spx,
    unsigned* __restrict__ gtab) {
    __shared__ unsigned tbl[TBLW];

    const int bx    = blockIdx.x;
    const int chunk = bx % NCHUNK;
    const int cg    = (bx / NCHUNK) % NCG;
    const int b     = bx / (NCHUNK * NCG);

    for (int i = threadIdx.x; i < TBLW; i += TPB) tbl[i] = ENEG;
    __syncthreads();

    const int c  = threadIdx.x & (CH - 1);
    const int pq = threadIdx.x >> 3;

    const float* imgc = img + ((size_t)(b * Cn + cg * CH + c)) * HWn
                            + (size_t)chunk * PIX;
    const int*   spxb = spx + (size_t)b * HWn + (size_t)chunk * PIX;

#pragma unroll 4
    for (int it = 0; it < ITERS; ++it) {
        const int q = pq + it * QPT;
        const float4 v = *(const float4*)(imgc + 4 * q);
        int4 k = *(const int4*)(spxb + 4 * q);
        k.x &= (Kseg - 1); k.y &= (Kseg - 1);
        k.z &= (Kseg - 1); k.w &= (Kseg - 1);
        atomicMax(tbl + (k.x * STR + c), enc(v.x));
        atomicMax(tbl + (k.y * STR + c), enc(v.y));
        atomicMax(tbl + (k.z * STR + c), enc(v.z));
        atomicMax(tbl + (k.w * STR + c), enc(v.w));
    }
    __syncthreads();

    // tbl[k*STR + j] -> out index (b*Cn + cg*CH + j)*K + k
    unsigned* base = gtab + (size_t)(b * Cn + cg * CH) * Kseg;
    for (int i = threadIdx.x; i < Kseg * CH; i += TPB) {
        const int k = i >> 3, j = i & (CH - 1);
        atomicMax(base + (size_t)j * Kseg + k, tbl[k * STR + j]);
    }
}

__global__ __launch_bounds__(256) void decode_inplace(unsigned* __restrict__ o) {
    const int i = blockIdx.x * 256 + threadIdx.x;
    const unsigned e = o[i];
    ((float*)o)[i] = dec(e);
}

extern "C" void kernel_launch(void* const* d_in, const int* in_sizes, int n_in,
                              void* d_out, int out_size, void* d_ws, size_t ws_size,
                              hipStream_t stream) {
    const float* img = (const float*)d_in[0];
    const int*   spx = (const int*)d_in[1];
    float*       out = (float*)d_out;

    const size_t need = (size_t)NBLK * TBLW * sizeof(unsigned);  // ~18.9 MB
    const int nOut256 = (Bn * Cn * Kseg) / 256;                  // 1024

    if (ws_size >= need) {
        unsigned* part = (unsigned*)d_ws;
        pool_partial<<<NBLK, TPB, 0, stream>>>(img, spx, part);
        pool_reduce<<<nOut256, 256, 0, stream>>>(part, out);
    } else {
        unsigned* gt = (unsigned*)d_out;
        init_enc_k<<<nOut256, 256, 0, stream>>>(gt);
        pool_atomic<<<NBLK, TPB, 0, stream>>>(img, spx, gt);
        decode_inplace<<<nOut256, 256, 0, stream>>>(gt);
    }
}

// Round 5
// 355.457 us; speedup vs baseline: 1.1018x; 1.0488x over previous
//
#include <hip/hip_runtime.h>
#include <hip/hip_bf16.h>

// SupPixPool: out[b,c,k] = max over pixels p with spx[b,p]==k of img[b,c,p].
// B=4, C=64, H=W=512, K=1024.
//
// Round-5 (= round-4 with compile fix): R3 structure (channels-across-lanes,
// padded stride-9 LDS table, direct global spx reads) + explicit depth-1
// software pipeline: prefetch iteration it+1's img float4 / spx int4 into
// registers BEFORE issuing iteration it's LDS atomics, so global-load latency
// (~200-900 cyc) overlaps the ds_max issue instead of chaining with it.
// img loads are nontemporal (read-once; keeps L2 for the x8-reused spx).
// Fix: __builtin_nontemporal_load needs a clang vector type, not
// HIP_vector_type -> use ext_vector_type(4) float.

constexpr int Kseg = 1024;
constexpr int Bn   = 4;
constexpr int Cn   = 64;
constexpr int HWn  = 512 * 512;

constexpr int CH     = 8;             // channels per block
constexpr int NCG    = Cn / CH;       // 8
constexpr int TPB    = 1024;
constexpr int NCHUNK = 16;            // pixel chunks per (b, cg)
constexpr int PIX    = HWn / NCHUNK;  // 16384 pixels per block
constexpr int STR    = 9;             // padded table stride (36 KB)
constexpr int TBLW   = Kseg * STR;    // 9216 words
constexpr int NBLK   = Bn * NCG * NCHUNK;  // 512
constexpr int QPT    = TPB / CH;      // 128 pixel-quads in flight
constexpr int ITERS  = PIX / (QPT * 4);    // 32

typedef float  vf4 __attribute__((ext_vector_type(4)));
typedef int    vi4 __attribute__((ext_vector_type(4)));

// order-preserving float->uint encoding: enc monotonic, unsigned max == fmax
constexpr unsigned ENEG = 0x007FFFFFu;  // enc(-inf)

__device__ __forceinline__ unsigned enc(float f) {
    unsigned u = __float_as_uint(f);
    return u ^ ((unsigned)((int)u >> 31) | 0x80000000u);
}
__device__ __forceinline__ float dec(unsigned e) {
    unsigned u = (e & 0x80000000u) ? (e ^ 0x80000000u) : ~e;
    return __uint_as_float(u);
}

__global__ __launch_bounds__(TPB, 8) void pool_partial(
    const float* __restrict__ img, const int* __restrict__ spx,
    unsigned* __restrict__ part) {
    __shared__ unsigned tbl[TBLW];  // 36 KB, [k][9] padded

    const int bx    = blockIdx.x;
    const int chunk = bx % NCHUNK;
    const int cg    = (bx / NCHUNK) % NCG;
    const int b     = bx / (NCHUNK * NCG);

    for (int i = threadIdx.x; i < TBLW; i += TPB) tbl[i] = ENEG;
    __syncthreads();

    const int c  = threadIdx.x & (CH - 1);   // channel lane 0..7
    const int pq = threadIdx.x >> 3;         // pixel-quad lane 0..127

    const float* imgc = img + ((size_t)(b * Cn + cg * CH + c)) * HWn
                            + (size_t)chunk * PIX;
    const int*   spxb = spx + (size_t)b * HWn + (size_t)chunk * PIX;

    // explicit depth-1 pipeline: loads for it+1 issued before atomics of it
    vf4 v = __builtin_nontemporal_load((const vf4*)(imgc + 4 * pq));
    vi4 k = *(const vi4*)(spxb + 4 * pq);

#pragma unroll 4
    for (int it = 0; it < ITERS; ++it) {
        vf4 vn;
        vi4 kn;
        if (it + 1 < ITERS) {
            const int qn = pq + (it + 1) * QPT;
            vn = __builtin_nontemporal_load((const vf4*)(imgc + 4 * qn));
            kn = *(const vi4*)(spxb + 4 * qn);
        }
        const int kx = (k.x & (Kseg - 1)) * STR + c;
        const int ky = (k.y & (Kseg - 1)) * STR + c;
        const int kz = (k.z & (Kseg - 1)) * STR + c;
        const int kw = (k.w & (Kseg - 1)) * STR + c;
        atomicMax(tbl + kx, enc(v.x));
        atomicMax(tbl + ky, enc(v.y));
        atomicMax(tbl + kz, enc(v.z));
        atomicMax(tbl + kw, enc(v.w));
        v = vn;
        k = kn;
    }
    __syncthreads();

    unsigned* dst = part + (size_t)bx * TBLW;
    for (int i = threadIdx.x; i < TBLW; i += TPB) dst[i] = tbl[i];
}

__global__ __launch_bounds__(256) void pool_reduce(
    const unsigned* __restrict__ part, float* __restrict__ out) {
    const int gid = blockIdx.x * 256 + threadIdx.x;  // [0, B*C*K)
    const int k  = gid & (Kseg - 1);
    const int cc = (gid >> 10) & (Cn - 1);
    const int b  = gid >> 16;
    const int cg = cc >> 3, j = cc & (CH - 1);

    unsigned acc = ENEG;
    const unsigned* p = part
        + ((size_t)(b * NCG + cg) * NCHUNK) * TBLW + k * STR + j;
    for (int ch = 0; ch < NCHUNK; ++ch)
        acc = max(acc, p[(size_t)ch * TBLW]);
    out[gid] = dec(acc);
}

// -------- fallback path (ws too small): global atomic merge into d_out -----
__global__ __launch_bounds__(256) void init_enc_k(unsigned* __restrict__ o) {
    o[blockIdx.x * 256 + threadIdx.x] = ENEG;
}

__global__ __launch_bounds__(TPB, 8) void pool_atomic(
    const float* __restrict__ img, const int* __restrict__ spx,
    unsigned* __restrict__ gtab) {
    __shared__ unsigned tbl[TBLW];

    const int bx    = blockIdx.x;
    const int chunk = bx % NCHUNK;
    const int cg    = (bx / NCHUNK) % NCG;
    const int b     = bx / (NCHUNK * NCG);

    for (int i = threadIdx.x; i < TBLW; i += TPB) tbl[i] = ENEG;
    __syncthreads();

    const int c  = threadIdx.x & (CH - 1);
    const int pq = threadIdx.x >> 3;

    const float* imgc = img + ((size_t)(b * Cn + cg * CH + c)) * HWn
                            + (size_t)chunk * PIX;
    const int*   spxb = spx + (size_t)b * HWn + (size_t)chunk * PIX;

#pragma unroll 4
    for (int it = 0; it < ITERS; ++it) {
        const int q = pq + it * QPT;
        const vf4 v = *(const vf4*)(imgc + 4 * q);
        vi4 k = *(const vi4*)(spxb + 4 * q);
        const int kx = (k.x & (Kseg - 1)) * STR + c;
        const int ky = (k.y & (Kseg - 1)) * STR + c;
        const int kz = (k.z & (Kseg - 1)) * STR + c;
        const int kw = (k.w & (Kseg - 1)) * STR + c;
        atomicMax(tbl + kx, enc(v.x));
        atomicMax(tbl + ky, enc(v.y));
        atomicMax(tbl + kz, enc(v.z));
        atomicMax(tbl + kw, enc(v.w));
    }
    __syncthreads();

    // tbl[k*STR + j] -> out index (b*Cn + cg*CH + j)*K + k
    unsigned* base = gtab + (size_t)(b * Cn + cg * CH) * Kseg;
    for (int i = threadIdx.x; i < Kseg * CH; i += TPB) {
        const int k = i >> 3, j = i & (CH - 1);
        atomicMax(base + (size_t)j * Kseg + k, tbl[k * STR + j]);
    }
}

__global__ __launch_bounds__(256) void decode_inplace(unsigned* __restrict__ o) {
    const int i = blockIdx.x * 256 + threadIdx.x;
    const unsigned e = o[i];
    ((float*)o)[i] = dec(e);
}

extern "C" void kernel_launch(void* const* d_in, const int* in_sizes, int n_in,
                              void* d_out, int out_size, void* d_ws, size_t ws_size,
                              hipStream_t stream) {
    const float* img = (const float*)d_in[0];
    const int*   spx = (const int*)d_in[1];
    float*       out = (float*)d_out;

    const size_t need = (size_t)NBLK * TBLW * sizeof(unsigned);  // ~18.9 MB
    const int nOut256 = (Bn * Cn * Kseg) / 256;                  // 1024

    if (ws_size >= need) {
        unsigned* part = (unsigned*)d_ws;
        pool_partial<<<NBLK, TPB, 0, stream>>>(img, spx, part);
        pool_reduce<<<nOut256, 256, 0, stream>>>(part, out);
    } else {
        unsigned* gt = (unsigned*)d_out;
        init_enc_k<<<nOut256, 256, 0, stream>>>(gt);
        pool_atomic<<<NBLK, TPB, 0, stream>>>(img, spx, gt);
        decode_inplace<<<nOut256, 256, 0, stream>>>(gt);
    }
}